// Round 5
// baseline (1741.358 us; speedup 1.0000x reference)
//
#include <hip/hip_runtime.h>
#include <hip/hip_bf16.h>

#define KD 6
#define DD 3
#define CO 32
#define CI 32
#define KC (KD * CO)  // 192

// ---------------- kernel 1: xg = x @ g -> bf16 ws [N, 192] ----------------
// 32 lanes per row-group, each lane-group handles 4 rows; lane o owns the 6
// consecutive output cols o*6..o*6+5. x broadcast via __shfl within the
// 32-lane group; g staged once per block (grid-stride over row tiles).
__global__ void xg_kernel(const float* __restrict__ x, const float* __restrict__ g,
                          ushort* __restrict__ xg, int N) {
    __shared__ float gs[CI * KC];  // 24 KiB
    for (int i = threadIdx.x; i < CI * KC; i += blockDim.x) gs[i] = g[i];
    __syncthreads();

    const int o    = threadIdx.x & 31;        // lane in 32-group
    const int grp  = threadIdx.x >> 5;        // 8 groups/block
    const int RPG  = 4;                       // rows per group
    const int rows_per_block = 8 * RPG;       // 32
    const int ntiles = (N + rows_per_block - 1) / rows_per_block;

    for (int tile = blockIdx.x; tile < ntiles; tile += gridDim.x) {
        const int n0 = tile * rows_per_block + grp * RPG;
        float xv[RPG];
#pragma unroll
        for (int r = 0; r < RPG; ++r) {
            int n = n0 + r;
            xv[r] = (n < N) ? x[n * CI + o] : 0.f;
        }
        float acc[RPG][6];
#pragma unroll
        for (int r = 0; r < RPG; ++r)
#pragma unroll
            for (int j = 0; j < 6; ++j) acc[r][j] = 0.f;

#pragma unroll
        for (int c = 0; c < CI; ++c) {
            const float* gr = &gs[c * KC + o * 6];
            float g0 = gr[0], g1 = gr[1], g2 = gr[2], g3 = gr[3], g4 = gr[4], g5 = gr[5];
#pragma unroll
            for (int r = 0; r < RPG; ++r) {
                float xc = __shfl(xv[r], c, 32);
                acc[r][0] = fmaf(xc, g0, acc[r][0]);
                acc[r][1] = fmaf(xc, g1, acc[r][1]);
                acc[r][2] = fmaf(xc, g2, acc[r][2]);
                acc[r][3] = fmaf(xc, g3, acc[r][3]);
                acc[r][4] = fmaf(xc, g4, acc[r][4]);
                acc[r][5] = fmaf(xc, g5, acc[r][5]);
            }
        }
        // store 6 bf16 (12 B) per row per lane, RNE rounding
#pragma unroll
        for (int r = 0; r < RPG; ++r) {
            int n = n0 + r;
            if (n >= N) break;
            uint* dst = (uint*)(xg + (size_t)n * KC + o * 6);
#pragma unroll
            for (int p = 0; p < 3; ++p) {
                __hip_bfloat16 lo = __float2bfloat16(acc[r][2 * p]);
                __hip_bfloat16 hi = __float2bfloat16(acc[r][2 * p + 1]);
                uint packed = (uint)__bfloat16_as_ushort(lo) |
                              ((uint)__bfloat16_as_ushort(hi) << 16);
                dst[p] = packed;
            }
        }
    }
}

// ---------------- kernel 2: per-edge message + atomic scatter ----------------
// 32 lanes per edge; lane o owns output channel o. xg gathered as bf16.
__global__ void edge_kernel(const int* __restrict__ ei, const float* __restrict__ pseudo,
                            const ushort* __restrict__ xg, const float* __restrict__ mu,
                            const float* __restrict__ sigma,
                            float* __restrict__ agg, float* __restrict__ cnt, int E) {
    float m[KD][DD], iv[KD][DD];
#pragma unroll
    for (int k = 0; k < KD; ++k)
#pragma unroll
        for (int d = 0; d < DD; ++d) {
            m[k][d] = mu[k * DD + d];
            float s = sigma[k * DD + d];
            iv[k][d] = -0.5f / (1e-15f + s * s);
        }
    const int o = threadIdx.x & 31;
    const int gpb = blockDim.x >> 5;
    int e0 = blockIdx.x * gpb + (threadIdx.x >> 5);
    const int estride = gridDim.x * gpb;
    for (int e = e0; e < E; e += estride) {
        const int src = ei[e];
        const int dst = ei[E + e];
        const float p0 = pseudo[e * 3 + 0];
        const float p1 = pseudo[e * 3 + 1];
        const float p2 = pseudo[e * 3 + 2];
        const ushort* xr = xg + (size_t)src * KC;
        float msg = 0.f;
#pragma unroll
        for (int k = 0; k < KD; ++k) {
            float d0 = p0 - m[k][0], d1 = p1 - m[k][1], d2 = p2 - m[k][2];
            float ex = d0 * d0 * iv[k][0] + d1 * d1 * iv[k][1] + d2 * d2 * iv[k][2];
            float w = __expf(ex);
            float xv = __uint_as_float(((uint)xr[k * CO + o]) << 16);  // bf16 -> f32
            msg = fmaf(w, xv, msg);
        }
        atomicAdd(&agg[(size_t)dst * CO + o], msg);  // coalesced across 32 lanes
        if (o == 0) atomicAdd(&cnt[dst], 1.0f);
    }
}

// ---------------- kernel 3: out = agg/max(cnt,1) + x@root + bias ----------------
__global__ void out_kernel(const float* __restrict__ x, const float* __restrict__ root,
                           const float* __restrict__ bias, const float* __restrict__ cnt,
                           float* __restrict__ out, int N) {
    __shared__ float rs[CI * CO];  // 4 KiB
    __shared__ float bs[CO];
    for (int i = threadIdx.x; i < CI * CO; i += blockDim.x) rs[i] = root[i];
    if (threadIdx.x < CO) bs[threadIdx.x] = bias[threadIdx.x];
    __syncthreads();
    int total = N * CO;
    for (int idx = blockIdx.x * blockDim.x + threadIdx.x; idx < total;
         idx += gridDim.x * blockDim.x) {
        int n = idx / CO;
        int o = idx - n * CO;
        const float* xr = x + n * CI;
        float acc = 0.f;
#pragma unroll
        for (int c = 0; c < CI; ++c) acc = fmaf(xr[c], rs[c * CO + o], acc);
        float cn = cnt[n];
        out[idx] = out[idx] / fmaxf(cn, 1.0f) + acc + bs[o];
    }
}

extern "C" void kernel_launch(void* const* d_in, const int* in_sizes, int n_in,
                              void* d_out, int out_size, void* d_ws, size_t ws_size,
                              hipStream_t stream) {
    const float* x      = (const float*)d_in[0];
    const int*   ei     = (const int*)d_in[1];
    const float* pseudo = (const float*)d_in[2];
    const float* g      = (const float*)d_in[3];
    const float* mu     = (const float*)d_in[4];
    const float* sigma  = (const float*)d_in[5];
    const float* root   = (const float*)d_in[6];
    const float* bias   = (const float*)d_in[7];
    float* out = (float*)d_out;

    const int N = in_sizes[0] / CI;
    const int E = in_sizes[1] / 2;

    ushort* xg = (ushort*)d_ws;                       // N*192 bf16 = 62.9 MB
    float* cnt = (float*)(xg + (size_t)N * KC);       // N floats

    hipMemsetAsync(d_out, 0, (size_t)out_size * sizeof(float), stream);
    hipMemsetAsync(cnt, 0, (size_t)N * sizeof(float), stream);

    const int blk = 256;

    xg_kernel<<<2048, blk, 0, stream>>>(x, g, xg, N);

    const int gpb = blk / 32;
    int grid2 = (E + gpb - 1) / gpb;
    if (grid2 > 16384) grid2 = 16384;
    edge_kernel<<<grid2, blk, 0, stream>>>(ei, pseudo, xg, mu, sigma, out, cnt, E);

    int grid3 = (N * CO + blk - 1) / blk;
    if (grid3 > 4096) grid3 = 4096;
    out_kernel<<<grid3, blk, 0, stream>>>(x, root, bias, cnt, out, N);
}

// Round 6
// 372.957 us; speedup vs baseline: 4.6691x; 4.6691x over previous
//
#include <hip/hip_runtime.h>
#include <hip/hip_bf16.h>

#define KD 6
#define DD 3
#define CO 32
#define CI 32
#define KC (KD * CO)   // 192
#define QP (KC / 2)    // 96 bf16 pairs per row

// ---------------- kernel 1: xg = x @ g -> bf16 ws [N, 192] ----------------
// Flat: thread idx owns bf16 PAIR q of row n (cols 2q,2q+1). One packed
// dword store at ((uint*)xg)[idx] -> consecutive dwords across lanes
// (fully coalesced; round-5's stride-12 scatter caused ~30x RMW traffic).
__global__ void xg_kernel(const float* __restrict__ x, const float* __restrict__ g,
                          uint* __restrict__ xg, int N) {
    __shared__ float gs[CI * KC];  // 24 KiB
    for (int i = threadIdx.x; i < CI * KC; i += blockDim.x) gs[i] = g[i];
    __syncthreads();
    const int total = N * QP;  // 15.7M
    for (int idx = blockIdx.x * blockDim.x + threadIdx.x; idx < total;
         idx += gridDim.x * blockDim.x) {
        const int n = idx / QP;
        const int q = idx - n * QP;          // pair index 0..95
        const float* xr = x + n * CI;
        const float* gq = gs + 2 * q;
        float a0 = 0.f, a1 = 0.f;
#pragma unroll
        for (int c = 0; c < CI; ++c) {
            float xc = xr[c];
            a0 = fmaf(xc, gq[c * KC], a0);
            a1 = fmaf(xc, gq[c * KC + 1], a1);
        }
        uint lo = (uint)__bfloat16_as_ushort(__float2bfloat16(a0));
        uint hi = (uint)__bfloat16_as_ushort(__float2bfloat16(a1));
        xg[idx] = lo | (hi << 16);
    }
}

// ---------------- kernel 2: per-edge message + atomic scatter ----------------
// 32 lanes per edge; lane o owns output channel o. xg gathered as bf16.
__global__ void edge_kernel(const int* __restrict__ ei, const float* __restrict__ pseudo,
                            const ushort* __restrict__ xg, const float* __restrict__ mu,
                            const float* __restrict__ sigma,
                            float* __restrict__ agg, float* __restrict__ cnt, int E) {
    float m[KD][DD], iv[KD][DD];
#pragma unroll
    for (int k = 0; k < KD; ++k)
#pragma unroll
        for (int d = 0; d < DD; ++d) {
            m[k][d] = mu[k * DD + d];
            float s = sigma[k * DD + d];
            iv[k][d] = -0.5f / (1e-15f + s * s);
        }
    const int o = threadIdx.x & 31;
    const int gpb = blockDim.x >> 5;
    int e0 = blockIdx.x * gpb + (threadIdx.x >> 5);
    const int estride = gridDim.x * gpb;
    for (int e = e0; e < E; e += estride) {
        const int src = ei[e];
        const int dst = ei[E + e];
        const float p0 = pseudo[e * 3 + 0];
        const float p1 = pseudo[e * 3 + 1];
        const float p2 = pseudo[e * 3 + 2];
        const ushort* xr = xg + (size_t)src * KC;
        float msg = 0.f;
#pragma unroll
        for (int k = 0; k < KD; ++k) {
            float d0 = p0 - m[k][0], d1 = p1 - m[k][1], d2 = p2 - m[k][2];
            float ex = d0 * d0 * iv[k][0] + d1 * d1 * iv[k][1] + d2 * d2 * iv[k][2];
            float w = __expf(ex);
            float xv = __uint_as_float(((uint)xr[k * CO + o]) << 16);  // bf16 -> f32
            msg = fmaf(w, xv, msg);
        }
        atomicAdd(&agg[(size_t)dst * CO + o], msg);  // coalesced across 32 lanes
        if (o == 0) atomicAdd(&cnt[dst], 1.0f);
    }
}

// ---------------- kernel 3: out = agg/max(cnt,1) + x@root + bias ----------------
__global__ void out_kernel(const float* __restrict__ x, const float* __restrict__ root,
                           const float* __restrict__ bias, const float* __restrict__ cnt,
                           float* __restrict__ out, int N) {
    __shared__ float rs[CI * CO];  // 4 KiB
    __shared__ float bs[CO];
    for (int i = threadIdx.x; i < CI * CO; i += blockDim.x) rs[i] = root[i];
    if (threadIdx.x < CO) bs[threadIdx.x] = bias[threadIdx.x];
    __syncthreads();
    int total = N * CO;
    for (int idx = blockIdx.x * blockDim.x + threadIdx.x; idx < total;
         idx += gridDim.x * blockDim.x) {
        int n = idx / CO;
        int o = idx - n * CO;
        const float* xr = x + n * CI;
        float acc = 0.f;
#pragma unroll
        for (int c = 0; c < CI; ++c) acc = fmaf(xr[c], rs[c * CO + o], acc);
        float cn = cnt[n];
        out[idx] = out[idx] / fmaxf(cn, 1.0f) + acc + bs[o];
    }
}

extern "C" void kernel_launch(void* const* d_in, const int* in_sizes, int n_in,
                              void* d_out, int out_size, void* d_ws, size_t ws_size,
                              hipStream_t stream) {
    const float* x      = (const float*)d_in[0];
    const int*   ei     = (const int*)d_in[1];
    const float* pseudo = (const float*)d_in[2];
    const float* g      = (const float*)d_in[3];
    const float* mu     = (const float*)d_in[4];
    const float* sigma  = (const float*)d_in[5];
    const float* root   = (const float*)d_in[6];
    const float* bias   = (const float*)d_in[7];
    float* out = (float*)d_out;

    const int N = in_sizes[0] / CI;
    const int E = in_sizes[1] / 2;

    ushort* xg = (ushort*)d_ws;                       // N*192 bf16 = 62.9 MB
    float* cnt = (float*)(xg + (size_t)N * KC);       // N floats

    hipMemsetAsync(d_out, 0, (size_t)out_size * sizeof(float), stream);
    hipMemsetAsync(cnt, 0, (size_t)N * sizeof(float), stream);

    const int blk = 256;

    int grid1 = (N * QP + blk - 1) / blk;
    if (grid1 > 4096) grid1 = 4096;
    xg_kernel<<<grid1, blk, 0, stream>>>(x, g, (uint*)xg, N);

    const int gpb = blk / 32;
    int grid2 = (E + gpb - 1) / gpb;
    if (grid2 > 16384) grid2 = 16384;
    edge_kernel<<<grid2, blk, 0, stream>>>(ei, pseudo, xg, mu, sigma, out, cnt, E);

    int grid3 = (N * CO + blk - 1) / blk;
    if (grid3 > 4096) grid3 = 4096;
    out_kernel<<<grid3, blk, 0, stream>>>(x, root, bias, cnt, out, N);
}